// Round 3
// baseline (927.831 us; speedup 1.0000x reference)
//
#include <hip/hip_runtime.h>
#include <math.h>

#define NN 100000
#define NE 1200000
#define INC 128
#define HIDC 64
#define EPSV 1e-5f
#define SCAN_BS 1024
#define NBLK ((NN + SCAN_BS - 1) / SCAN_BS)   // 98

typedef float f4 __attribute__((ext_vector_type(4)));

// ---------------- CSR build: count, scan, fill ----------------

__global__ void k_count(const int* __restrict__ dst, int* cnt) {
    int e = blockIdx.x * blockDim.x + threadIdx.x;
    if (e < NE) atomicAdd(&cnt[dst[e]], 1);
}

__global__ __launch_bounds__(256) void k_scan1(const int* __restrict__ cnt, int* bsum) {
    __shared__ int part[256];
    int base = blockIdx.x * SCAN_BS + threadIdx.x * 4;
    int s = 0;
#pragma unroll
    for (int j = 0; j < 4; ++j) { int i = base + j; if (i < NN) s += cnt[i]; }
    part[threadIdx.x] = s;
    __syncthreads();
    for (int off = 128; off > 0; off >>= 1) {
        if (threadIdx.x < off) part[threadIdx.x] += part[threadIdx.x + off];
        __syncthreads();
    }
    if (threadIdx.x == 0) bsum[blockIdx.x] = part[0];
}

__global__ void k_scan2(int* bsum) {   // exclusive scan of NBLK block sums
    __shared__ int s[128];
    int t = threadIdx.x;
    if (t < NBLK) s[t] = bsum[t];
    __syncthreads();
    if (t == 0) {
        int acc = 0;
        for (int i = 0; i < NBLK; ++i) { int v = s[i]; s[i] = acc; acc += v; }
    }
    __syncthreads();
    if (t < NBLK) bsum[t] = s[t];
}

__global__ __launch_bounds__(256) void k_scan3(const int* __restrict__ cnt,
                                               const int* __restrict__ boff,
                                               int* cursor, float* dinv) {
    __shared__ int part[256];
    int t = threadIdx.x;
    int base = blockIdx.x * SCAN_BS + t * 4;
    int v[4]; int s = 0;
#pragma unroll
    for (int j = 0; j < 4; ++j) { int i = base + j; v[j] = (i < NN) ? cnt[i] : 0; s += v[j]; }
    part[t] = s;
    __syncthreads();
    for (int off = 1; off < 256; off <<= 1) {
        int x = (t >= off) ? part[t - off] : 0;
        __syncthreads();
        part[t] += x;
        __syncthreads();
    }
    int run = boff[blockIdx.x] + part[t] - s;
#pragma unroll
    for (int j = 0; j < 4; ++j) {
        int i = base + j;
        if (i < NN) {
            cursor[i] = run;
            dinv[i] = rsqrtf((float)v[j] + 1.0f);   // deg = indeg + self-loop
            run += v[j];
        }
    }
}

__global__ void k_fill(const int* __restrict__ src, const int* __restrict__ dst,
                       int* cursor, int* srcSorted) {
    int e = blockIdx.x * blockDim.x + threadIdx.x;
    if (e < NE) {
        int pos = atomicAdd(&cursor[dst[e]], 1);
        srcSorted[pos] = src[e];
    }
}

// ---------------- layer-1 GEMM: h'[n] = dinv[n] * (x[n] @ W1) ----------------
// block: 32 nodes x 64 ch; thread: 2 nodes x 4 ch (f4 acc); x tile in LDS, W via L1.
__global__ __launch_bounds__(256) void k_gemm1(
    const float* __restrict__ x, const float* __restrict__ W,
    const float* __restrict__ dinv, float* __restrict__ hp) {
    __shared__ float xs[32][132];           // pad 132: ng-row stride 264 dw == 8 mod 32
    int tid = threadIdx.x;
    int nodeBase = blockIdx.x * 32;
    // stage x tile (32x128 fp32) coalesced
    for (int idx = tid; idx < 32 * 128 / 4; idx += 256) {
        int f = idx * 4; int r = f >> 7, k = f & 127;
        f4 v = {0.f, 0.f, 0.f, 0.f};
        if (nodeBase + r < NN) v = *(const f4*)&x[(size_t)(nodeBase + r) * INC + k];
        *(f4*)&xs[r][k] = v;
    }
    __syncthreads();
    int cg = tid & 15, ng = tid >> 4;       // 16 ch-groups x 16 node-groups
    int c0 = cg * 4, n0 = ng * 2;
    f4 acc0 = {0.f,0.f,0.f,0.f}, acc1 = {0.f,0.f,0.f,0.f};
    for (int k0 = 0; k0 < INC; k0 += 4) {
        f4 xv0 = *(const f4*)&xs[n0][k0];
        f4 xv1 = *(const f4*)&xs[n0 + 1][k0];
#pragma unroll
        for (int kk = 0; kk < 4; ++kk) {
            f4 wv = *(const f4*)&W[(size_t)(k0 + kk) * HIDC + c0];
            acc0 += xv0[kk] * wv;
            acc1 += xv1[kk] * wv;
        }
    }
    int nA = nodeBase + n0, nB = nA + 1;
    if (nA < NN) *(f4*)&hp[(size_t)nA * HIDC + c0] = acc0 * dinv[nA];
    if (nB < NN) *(f4*)&hp[(size_t)nB * HIDC + c0] = acc1 * dinv[nB];
}

// ---------------- layer-2 GEMM with fused BN+ReLU on the staged load ----------------
__global__ __launch_bounds__(256) void k_gemm2(
    const float* __restrict__ agg, const float* __restrict__ W,
    const float* __restrict__ scale, const float* __restrict__ shift,
    const float* __restrict__ dinv, float* __restrict__ hp) {
    __shared__ float xs[32][68];            // pad 68: ng-row stride 136 dw == 8 mod 32
    int tid = threadIdx.x;
    int nodeBase = blockIdx.x * 32;
    for (int idx = tid; idx < 32 * 64 / 4; idx += 256) {
        int f = idx * 4; int r = f >> 6, c = f & 63;
        f4 v = {0.f, 0.f, 0.f, 0.f};
        if (nodeBase + r < NN) {
            v = *(const f4*)&agg[(size_t)(nodeBase + r) * HIDC + c];
            f4 sc = *(const f4*)&scale[c];
            f4 sh = *(const f4*)&shift[c];
            v = v * sc + sh;
#pragma unroll
            for (int j = 0; j < 4; ++j) v[j] = fmaxf(v[j], 0.f);
        }
        *(f4*)&xs[r][c] = v;
    }
    __syncthreads();
    int cg = tid & 15, ng = tid >> 4;
    int c0 = cg * 4, n0 = ng * 2;
    f4 acc0 = {0.f,0.f,0.f,0.f}, acc1 = {0.f,0.f,0.f,0.f};
    for (int k0 = 0; k0 < HIDC; k0 += 4) {
        f4 xv0 = *(const f4*)&xs[n0][k0];
        f4 xv1 = *(const f4*)&xs[n0 + 1][k0];
#pragma unroll
        for (int kk = 0; kk < 4; ++kk) {
            f4 wv = *(const f4*)&W[(size_t)(k0 + kk) * HIDC + c0];
            acc0 += xv0[kk] * wv;
            acc1 += xv1[kk] * wv;
        }
    }
    int nA = nodeBase + n0, nB = nA + 1;
    if (nA < NN) *(f4*)&hp[(size_t)nA * HIDC + c0] = acc0 * dinv[nA];
    if (nB < NN) *(f4*)&hp[(size_t)nB * HIDC + c0] = acc1 * dinv[nB];
}

// ---------------- CSR gather: agg[n] = dinv[n] * (h'[n] + sum h'[s]) ----------------
__global__ __launch_bounds__(256) void k_gather(
    const int* __restrict__ eend, const int* __restrict__ srcSorted,
    const float* __restrict__ dinv, const float* __restrict__ hp,
    float* __restrict__ agg) {
    int wid = threadIdx.x >> 6, lane = threadIdx.x & 63;
    int n = blockIdx.x * 4 + wid;
    if (n >= NN) return;
    int beg = n ? eend[n - 1] : 0;
    int end = eend[n];
    float acc = hp[(size_t)n * HIDC + lane];   // self-loop
    for (int base = beg; base < end; base += 64) {
        int m = end - base; if (m > 64) m = 64;
        int si = (base + lane < end) ? srcSorted[base + lane] : 0;
        int j = 0;
        for (; j + 4 <= m; j += 4) {
            int s0 = __shfl(si, j), s1 = __shfl(si, j + 1);
            int s2 = __shfl(si, j + 2), s3 = __shfl(si, j + 3);
            float v0 = hp[(size_t)s0 * HIDC + lane];
            float v1 = hp[(size_t)s1 * HIDC + lane];
            float v2 = hp[(size_t)s2 * HIDC + lane];
            float v3 = hp[(size_t)s3 * HIDC + lane];
            acc += v0; acc += v1; acc += v2; acc += v3;
        }
        for (; j < m; ++j) {
            int s = __shfl(si, j);
            acc += hp[(size_t)s * HIDC + lane];
        }
    }
    agg[(size_t)n * HIDC + lane] = dinv[n] * acc;
}

// ---------------- BN statistics ----------------
__global__ __launch_bounds__(256) void k_stats(
    const float* __restrict__ agg, float* gsum, float* gsq) {
    __shared__ float ls[256], lq[256];
    int tid = threadIdx.x;
    int c = tid & 63, r = tid >> 6;
    float s = 0.0f, q = 0.0f;
    for (int n = blockIdx.x * 4 + r; n < NN; n += gridDim.x * 4) {
        float v = agg[(size_t)n * HIDC + c];
        s += v; q += v * v;
    }
    ls[tid] = s; lq[tid] = q;
    __syncthreads();
    if (tid < 64) {
        s = ls[tid] + ls[tid + 64] + ls[tid + 128] + ls[tid + 192];
        q = lq[tid] + lq[tid + 64] + lq[tid + 128] + lq[tid + 192];
        atomicAdd(&gsum[c], s);
        atomicAdd(&gsq[c], q);
    }
}

__global__ void k_bnfin(const float* __restrict__ gsum, const float* __restrict__ gsq,
                        const float* __restrict__ g, const float* __restrict__ be,
                        float* scale, float* shift) {
    int c = threadIdx.x;
    if (c < HIDC) {
        float mu = gsum[c] * (1.0f / NN);
        float var = gsq[c] * (1.0f / NN) - mu * mu;
        float inv = rsqrtf(var + EPSV);
        float sc = g[c] * inv;
        scale[c] = sc;
        shift[c] = be[c] - mu * sc;
    }
}

// ---------------- MLP head with fused BN+ReLU on the load ----------------
__global__ __launch_bounds__(256) void k_mlp(
    const float* __restrict__ agg, const float* __restrict__ scale,
    const float* __restrict__ shift,
    const float* __restrict__ Wm1, const float* __restrict__ bm1,
    const float* __restrict__ Wm2, const float* __restrict__ bm2,
    const float* __restrict__ Wm3, const float* __restrict__ bm3,
    float* __restrict__ out) {
    int n = blockIdx.x * blockDim.x + threadIdx.x;
    if (n >= NN) return;
    float h[HIDC];
#pragma unroll
    for (int c = 0; c < HIDC; ++c)
        h[c] = fmaxf(agg[(size_t)n * HIDC + c] * scale[c] + shift[c], 0.0f);
    float a1[32];
#pragma unroll
    for (int j = 0; j < 32; ++j) {
        float acc = bm1[j];
#pragma unroll
        for (int c = 0; c < HIDC; ++c) acc += h[c] * Wm1[c * 32 + j];
        a1[j] = fmaxf(acc, 0.0f);
    }
    float a2[16];
#pragma unroll
    for (int j = 0; j < 16; ++j) {
        float acc = bm2[j];
#pragma unroll
        for (int c = 0; c < 32; ++c) acc += a1[c] * Wm2[c * 16 + j];
        a2[j] = fmaxf(acc, 0.0f);
    }
    float z = bm3[0];
#pragma unroll
    for (int c = 0; c < 16; ++c) z += a2[c] * Wm3[c];
    out[n] = 1.0f / (1.0f + expf(-z));
}

extern "C" void kernel_launch(void* const* d_in, const int* in_sizes, int n_in,
                              void* d_out, int out_size, void* d_ws, size_t ws_size,
                              hipStream_t stream) {
    const float* x   = (const float*)d_in[0];
    const int*   ei  = (const int*)d_in[1];
    const float* W1  = (const float*)d_in[2];
    // b1 (d_in[3]) cancels in BatchNorm
    const float* g1  = (const float*)d_in[4];
    const float* be1 = (const float*)d_in[5];
    const float* W2  = (const float*)d_in[6];
    // b2 (d_in[7]) cancels in BatchNorm
    const float* g2  = (const float*)d_in[8];
    const float* be2 = (const float*)d_in[9];
    const float* Wm1 = (const float*)d_in[10];
    const float* bm1 = (const float*)d_in[11];
    const float* Wm2 = (const float*)d_in[12];
    const float* bm2 = (const float*)d_in[13];
    const float* Wm3 = (const float*)d_in[14];
    const float* bm3 = (const float*)d_in[15];
    float* out = (float*)d_out;

    const int* srcI = ei;
    const int* dstI = ei + NE;

    int*   cnt       = (int*)d_ws;                      // NN
    int*   bsum      = cnt + NN;                        // 128
    int*   cursor    = bsum + 128;                      // NN (start -> end offsets after fill)
    int*   srcSorted = cursor + NN;                     // NE
    float* dinv      = (float*)(srcSorted + NE);        // NN
    float* bufH      = dinv + NN;                       // NN*64  (h' = dinv*h)
    float* bufA      = bufH + (size_t)NN * HIDC;        // NN*64
    float* stats     = bufA + (size_t)NN * HIDC;        // 512
    float *sum1 = stats,       *sq1 = stats + 64;
    float *sum2 = stats + 128, *sq2 = stats + 192;
    float *scale1 = stats + 256, *shift1 = stats + 320;
    float *scale2 = stats + 384, *shift2 = stats + 448;

    hipMemsetAsync(cnt, 0, NN * sizeof(int), stream);
    hipMemsetAsync(stats, 0, 256 * sizeof(float), stream);

    // CSR build (by destination)
    k_count<<<(NE + 255) / 256, 256, 0, stream>>>(dstI, cnt);
    k_scan1<<<NBLK, 256, 0, stream>>>(cnt, bsum);
    k_scan2<<<1, 128, 0, stream>>>(bsum);
    k_scan3<<<NBLK, 256, 0, stream>>>(cnt, bsum, cursor, dinv);
    k_fill<<<(NE + 255) / 256, 256, 0, stream>>>(srcI, dstI, cursor, srcSorted);

    // layer 1
    k_gemm1<<<(NN + 31) / 32, 256, 0, stream>>>(x, W1, dinv, bufH);
    k_gather<<<(NN + 3) / 4, 256, 0, stream>>>(cursor, srcSorted, dinv, bufH, bufA);
    k_stats<<<512, 256, 0, stream>>>(bufA, sum1, sq1);
    k_bnfin<<<1, 64, 0, stream>>>(sum1, sq1, g1, be1, scale1, shift1);

    // layer 2
    k_gemm2<<<(NN + 31) / 32, 256, 0, stream>>>(bufA, W2, scale1, shift1, dinv, bufH);
    k_gather<<<(NN + 3) / 4, 256, 0, stream>>>(cursor, srcSorted, dinv, bufH, bufA);
    k_stats<<<512, 256, 0, stream>>>(bufA, sum2, sq2);
    k_bnfin<<<1, 64, 0, stream>>>(sum2, sq2, g2, be2, scale2, shift2);

    // MLP head
    k_mlp<<<(NN + 255) / 256, 256, 0, stream>>>(bufA, scale2, shift2,
                                                Wm1, bm1, Wm2, bm2, Wm3, bm3, out);
}

// Round 4
// 392.666 us; speedup vs baseline: 2.3629x; 2.3629x over previous
//
#include <hip/hip_runtime.h>
#include <math.h>

#define NN 100000
#define NE 1200000
#define INC 128
#define HIDC 64
#define EPSV 1e-5f
#define SCAN_BS 1024
#define NBLK ((NN + SCAN_BS - 1) / SCAN_BS)   // 98

typedef float f4 __attribute__((ext_vector_type(4)));

// ---------------- CSR build: count, scan, fill ----------------

__global__ void k_count(const int* __restrict__ dst, int* cnt) {
    int e = blockIdx.x * blockDim.x + threadIdx.x;
    if (e < NE) atomicAdd(&cnt[dst[e]], 1);
}

__global__ __launch_bounds__(256) void k_scan1(const int* __restrict__ cnt, int* bsum) {
    __shared__ int part[256];
    int base = blockIdx.x * SCAN_BS + threadIdx.x * 4;
    int s = 0;
#pragma unroll
    for (int j = 0; j < 4; ++j) { int i = base + j; if (i < NN) s += cnt[i]; }
    part[threadIdx.x] = s;
    __syncthreads();
    for (int off = 128; off > 0; off >>= 1) {
        if (threadIdx.x < off) part[threadIdx.x] += part[threadIdx.x + off];
        __syncthreads();
    }
    if (threadIdx.x == 0) bsum[blockIdx.x] = part[0];
}

__global__ void k_scan2(int* bsum) {   // exclusive scan of NBLK block sums
    __shared__ int s[128];
    int t = threadIdx.x;
    if (t < NBLK) s[t] = bsum[t];
    __syncthreads();
    if (t == 0) {
        int acc = 0;
        for (int i = 0; i < NBLK; ++i) { int v = s[i]; s[i] = acc; acc += v; }
    }
    __syncthreads();
    if (t < NBLK) bsum[t] = s[t];
}

__global__ __launch_bounds__(256) void k_scan3(const int* __restrict__ cnt,
                                               const int* __restrict__ boff,
                                               int* cursor, float* dinv) {
    __shared__ int part[256];
    int t = threadIdx.x;
    int base = blockIdx.x * SCAN_BS + t * 4;
    int v[4]; int s = 0;
#pragma unroll
    for (int j = 0; j < 4; ++j) { int i = base + j; v[j] = (i < NN) ? cnt[i] : 0; s += v[j]; }
    part[t] = s;
    __syncthreads();
    for (int off = 1; off < 256; off <<= 1) {
        int x = (t >= off) ? part[t - off] : 0;
        __syncthreads();
        part[t] += x;
        __syncthreads();
    }
    int run = boff[blockIdx.x] + part[t] - s;
#pragma unroll
    for (int j = 0; j < 4; ++j) {
        int i = base + j;
        if (i < NN) {
            cursor[i] = run;
            dinv[i] = rsqrtf((float)v[j] + 1.0f);   // deg = indeg + self-loop
            run += v[j];
        }
    }
}

__global__ void k_fill(const int* __restrict__ src, const int* __restrict__ dst,
                       int* cursor, int* srcSorted) {
    int e = blockIdx.x * blockDim.x + threadIdx.x;
    if (e < NE) {
        int pos = atomicAdd(&cursor[dst[e]], 1);
        srcSorted[pos] = src[e];
    }
}

// ---------------- layer-1 GEMM: h'[n] = dinv[n] * (x[n] @ W1) ----------------
// block: 64 nodes x 64 ch; thread: 4 nodes x 4 ch. x tile + W both in LDS.
// x rows skew-rotated by (row&3)*4 floats -> conflict-free b128, zero padding.
__global__ __launch_bounds__(256) void k_gemm1(
    const float* __restrict__ x, const float* __restrict__ W,
    const float* __restrict__ dinv, float* __restrict__ hp) {
    __shared__ float xs[64 * 128];
    __shared__ float wsh[128 * 64];
    int tid = threadIdx.x;
    int nodeBase = blockIdx.x * 64;
    // stage W (128x64) linear
    for (int idx = tid; idx < 128 * 64 / 4; idx += 256)
        *(f4*)&wsh[idx * 4] = *(const f4*)&W[idx * 4];
    // stage x tile (64x128), rotated within row
    for (int idx = tid; idx < 64 * 32; idx += 256) {
        int r = idx >> 5, k = (idx & 31) * 4;
        f4 v = {0.f, 0.f, 0.f, 0.f};
        int n = nodeBase + r;
        if (n < NN) v = *(const f4*)&x[(size_t)n * INC + k];
        *(f4*)&xs[r * 128 + ((k + (r & 3) * 4) & 127)] = v;
    }
    __syncthreads();
    int cg = tid & 15, ng = tid >> 4;
    int c0 = cg * 4, n0 = ng * 4;
    f4 acc0 = {0.f,0.f,0.f,0.f}, acc1 = acc0, acc2 = acc0, acc3 = acc0;
#pragma unroll 2
    for (int k0 = 0; k0 < INC; k0 += 4) {
        f4 xv0 = *(const f4*)&xs[(n0 + 0) * 128 + ((k0 + 0)  & 127)];
        f4 xv1 = *(const f4*)&xs[(n0 + 1) * 128 + ((k0 + 4)  & 127)];
        f4 xv2 = *(const f4*)&xs[(n0 + 2) * 128 + ((k0 + 8)  & 127)];
        f4 xv3 = *(const f4*)&xs[(n0 + 3) * 128 + ((k0 + 12) & 127)];
#pragma unroll
        for (int kk = 0; kk < 4; ++kk) {
            f4 wv = *(const f4*)&wsh[(k0 + kk) * 64 + c0];
            acc0 += xv0[kk] * wv;
            acc1 += xv1[kk] * wv;
            acc2 += xv2[kk] * wv;
            acc3 += xv3[kk] * wv;
        }
    }
    int n = nodeBase + n0;
    if (n + 0 < NN) *(f4*)&hp[(size_t)(n + 0) * HIDC + c0] = acc0 * dinv[n + 0];
    if (n + 1 < NN) *(f4*)&hp[(size_t)(n + 1) * HIDC + c0] = acc1 * dinv[n + 1];
    if (n + 2 < NN) *(f4*)&hp[(size_t)(n + 2) * HIDC + c0] = acc2 * dinv[n + 2];
    if (n + 3 < NN) *(f4*)&hp[(size_t)(n + 3) * HIDC + c0] = acc3 * dinv[n + 3];
}

// ---------------- layer-2 GEMM, BN+ReLU fused on the staged load ----------------
__global__ __launch_bounds__(256) void k_gemm2(
    const float* __restrict__ agg, const float* __restrict__ W,
    const float* __restrict__ scale, const float* __restrict__ shift,
    const float* __restrict__ dinv, float* __restrict__ hp) {
    __shared__ float xs[64 * 64];
    __shared__ float wsh[64 * 64];
    int tid = threadIdx.x;
    int nodeBase = blockIdx.x * 64;
    for (int idx = tid; idx < 64 * 64 / 4; idx += 256)
        *(f4*)&wsh[idx * 4] = *(const f4*)&W[idx * 4];
    for (int idx = tid; idx < 64 * 16; idx += 256) {
        int r = idx >> 4, c = (idx & 15) * 4;
        f4 v = {0.f, 0.f, 0.f, 0.f};
        int n = nodeBase + r;
        if (n < NN) {
            v = *(const f4*)&agg[(size_t)n * HIDC + c];
            f4 sc = *(const f4*)&scale[c];
            f4 sh = *(const f4*)&shift[c];
            v = v * sc + sh;
#pragma unroll
            for (int j = 0; j < 4; ++j) v[j] = fmaxf(v[j], 0.f);
        }
        *(f4*)&xs[r * 64 + ((c + (r & 3) * 4) & 63)] = v;
    }
    __syncthreads();
    int cg = tid & 15, ng = tid >> 4;
    int c0 = cg * 4, n0 = ng * 4;
    f4 acc0 = {0.f,0.f,0.f,0.f}, acc1 = acc0, acc2 = acc0, acc3 = acc0;
#pragma unroll 2
    for (int k0 = 0; k0 < HIDC; k0 += 4) {
        f4 xv0 = *(const f4*)&xs[(n0 + 0) * 64 + ((k0 + 0)  & 63)];
        f4 xv1 = *(const f4*)&xs[(n0 + 1) * 64 + ((k0 + 4)  & 63)];
        f4 xv2 = *(const f4*)&xs[(n0 + 2) * 64 + ((k0 + 8)  & 63)];
        f4 xv3 = *(const f4*)&xs[(n0 + 3) * 64 + ((k0 + 12) & 63)];
#pragma unroll
        for (int kk = 0; kk < 4; ++kk) {
            f4 wv = *(const f4*)&wsh[(k0 + kk) * 64 + c0];
            acc0 += xv0[kk] * wv;
            acc1 += xv1[kk] * wv;
            acc2 += xv2[kk] * wv;
            acc3 += xv3[kk] * wv;
        }
    }
    int n = nodeBase + n0;
    if (n + 0 < NN) *(f4*)&hp[(size_t)(n + 0) * HIDC + c0] = acc0 * dinv[n + 0];
    if (n + 1 < NN) *(f4*)&hp[(size_t)(n + 1) * HIDC + c0] = acc1 * dinv[n + 1];
    if (n + 2 < NN) *(f4*)&hp[(size_t)(n + 2) * HIDC + c0] = acc2 * dinv[n + 2];
    if (n + 3 < NN) *(f4*)&hp[(size_t)(n + 3) * HIDC + c0] = acc3 * dinv[n + 3];
}

// ---------------- CSR gather: agg[n] = dinv[n] * (h'[n] + sum h'[s]) ----------------
__global__ __launch_bounds__(256) void k_gather(
    const int* __restrict__ eend, const int* __restrict__ srcSorted,
    const float* __restrict__ dinv, const float* __restrict__ hp,
    float* __restrict__ agg) {
    int wid = threadIdx.x >> 6, lane = threadIdx.x & 63;
    int n = blockIdx.x * 4 + wid;
    if (n >= NN) return;
    int beg = n ? eend[n - 1] : 0;
    int end = eend[n];
    float acc = hp[(size_t)n * HIDC + lane];   // self-loop
    for (int base = beg; base < end; base += 64) {
        int m = end - base; if (m > 64) m = 64;
        int si = (base + lane < end) ? srcSorted[base + lane] : 0;
        int j = 0;
        for (; j + 8 <= m; j += 8) {
            int s0 = __shfl(si, j),     s1 = __shfl(si, j + 1);
            int s2 = __shfl(si, j + 2), s3 = __shfl(si, j + 3);
            int s4 = __shfl(si, j + 4), s5 = __shfl(si, j + 5);
            int s6 = __shfl(si, j + 6), s7 = __shfl(si, j + 7);
            float v0 = hp[(size_t)s0 * HIDC + lane];
            float v1 = hp[(size_t)s1 * HIDC + lane];
            float v2 = hp[(size_t)s2 * HIDC + lane];
            float v3 = hp[(size_t)s3 * HIDC + lane];
            float v4 = hp[(size_t)s4 * HIDC + lane];
            float v5 = hp[(size_t)s5 * HIDC + lane];
            float v6 = hp[(size_t)s6 * HIDC + lane];
            float v7 = hp[(size_t)s7 * HIDC + lane];
            acc += ((v0 + v1) + (v2 + v3)) + ((v4 + v5) + (v6 + v7));
        }
        for (; j + 2 <= m; j += 2) {
            int s0 = __shfl(si, j), s1 = __shfl(si, j + 1);
            float v0 = hp[(size_t)s0 * HIDC + lane];
            float v1 = hp[(size_t)s1 * HIDC + lane];
            acc += v0 + v1;
        }
        if (j < m) {
            int s = __shfl(si, j);
            acc += hp[(size_t)s * HIDC + lane];
        }
    }
    agg[(size_t)n * HIDC + lane] = dinv[n] * acc;
}

// ---------------- BN statistics ----------------
__global__ __launch_bounds__(256) void k_stats(
    const float* __restrict__ agg, float* gsum, float* gsq) {
    __shared__ float ls[256], lq[256];
    int tid = threadIdx.x;
    int c = tid & 63, r = tid >> 6;
    float s = 0.0f, q = 0.0f;
    for (int n = blockIdx.x * 4 + r; n < NN; n += gridDim.x * 4) {
        float v = agg[(size_t)n * HIDC + c];
        s += v; q += v * v;
    }
    ls[tid] = s; lq[tid] = q;
    __syncthreads();
    if (tid < 64) {
        s = ls[tid] + ls[tid + 64] + ls[tid + 128] + ls[tid + 192];
        q = lq[tid] + lq[tid + 64] + lq[tid + 128] + lq[tid + 192];
        atomicAdd(&gsum[c], s);
        atomicAdd(&gsq[c], q);
    }
}

__global__ void k_bnfin(const float* __restrict__ gsum, const float* __restrict__ gsq,
                        const float* __restrict__ g, const float* __restrict__ be,
                        float* scale, float* shift) {
    int c = threadIdx.x;
    if (c < HIDC) {
        float mu = gsum[c] * (1.0f / NN);
        float var = gsq[c] * (1.0f / NN) - mu * mu;
        float inv = rsqrtf(var + EPSV);
        float sc = g[c] * inv;
        scale[c] = sc;
        shift[c] = be[c] - mu * sc;
    }
}

// ---------------- MLP head with fused BN+ReLU on the load ----------------
__global__ __launch_bounds__(256) void k_mlp(
    const float* __restrict__ agg, const float* __restrict__ scale,
    const float* __restrict__ shift,
    const float* __restrict__ Wm1, const float* __restrict__ bm1,
    const float* __restrict__ Wm2, const float* __restrict__ bm2,
    const float* __restrict__ Wm3, const float* __restrict__ bm3,
    float* __restrict__ out) {
    int n = blockIdx.x * blockDim.x + threadIdx.x;
    if (n >= NN) return;
    float h[HIDC];
#pragma unroll
    for (int c = 0; c < HIDC; ++c)
        h[c] = fmaxf(agg[(size_t)n * HIDC + c] * scale[c] + shift[c], 0.0f);
    float a1[32];
#pragma unroll
    for (int j = 0; j < 32; ++j) {
        float acc = bm1[j];
#pragma unroll
        for (int c = 0; c < HIDC; ++c) acc += h[c] * Wm1[c * 32 + j];
        a1[j] = fmaxf(acc, 0.0f);
    }
    float a2[16];
#pragma unroll
    for (int j = 0; j < 16; ++j) {
        float acc = bm2[j];
#pragma unroll
        for (int c = 0; c < 32; ++c) acc += a1[c] * Wm2[c * 16 + j];
        a2[j] = fmaxf(acc, 0.0f);
    }
    float z = bm3[0];
#pragma unroll
    for (int c = 0; c < 16; ++c) z += a2[c] * Wm3[c];
    out[n] = 1.0f / (1.0f + expf(-z));
}

extern "C" void kernel_launch(void* const* d_in, const int* in_sizes, int n_in,
                              void* d_out, int out_size, void* d_ws, size_t ws_size,
                              hipStream_t stream) {
    const float* x   = (const float*)d_in[0];
    const int*   ei  = (const int*)d_in[1];
    const float* W1  = (const float*)d_in[2];
    // b1 (d_in[3]) cancels in BatchNorm
    const float* g1  = (const float*)d_in[4];
    const float* be1 = (const float*)d_in[5];
    const float* W2  = (const float*)d_in[6];
    // b2 (d_in[7]) cancels in BatchNorm
    const float* g2  = (const float*)d_in[8];
    const float* be2 = (const float*)d_in[9];
    const float* Wm1 = (const float*)d_in[10];
    const float* bm1 = (const float*)d_in[11];
    const float* Wm2 = (const float*)d_in[12];
    const float* bm2 = (const float*)d_in[13];
    const float* Wm3 = (const float*)d_in[14];
    const float* bm3 = (const float*)d_in[15];
    float* out = (float*)d_out;

    const int* srcI = ei;
    const int* dstI = ei + NE;

    int*   cnt       = (int*)d_ws;                      // NN
    int*   bsum      = cnt + NN;                        // 128
    int*   cursor    = bsum + 128;                      // NN (start -> end offsets after fill)
    int*   srcSorted = cursor + NN;                     // NE
    float* dinv      = (float*)(srcSorted + NE);        // NN
    float* bufH      = dinv + NN;                       // NN*64  (h' = dinv*h)
    float* bufA      = bufH + (size_t)NN * HIDC;        // NN*64
    float* stats     = bufA + (size_t)NN * HIDC;        // 512
    float *sum1 = stats,       *sq1 = stats + 64;
    float *sum2 = stats + 128, *sq2 = stats + 192;
    float *scale1 = stats + 256, *shift1 = stats + 320;
    float *scale2 = stats + 384, *shift2 = stats + 448;

    hipMemsetAsync(cnt, 0, NN * sizeof(int), stream);
    hipMemsetAsync(stats, 0, 256 * sizeof(float), stream);

    // CSR build (by destination)
    k_count<<<(NE + 255) / 256, 256, 0, stream>>>(dstI, cnt);
    k_scan1<<<NBLK, 256, 0, stream>>>(cnt, bsum);
    k_scan2<<<1, 128, 0, stream>>>(bsum);
    k_scan3<<<NBLK, 256, 0, stream>>>(cnt, bsum, cursor, dinv);
    k_fill<<<(NE + 255) / 256, 256, 0, stream>>>(srcI, dstI, cursor, srcSorted);

    // layer 1
    k_gemm1<<<(NN + 63) / 64, 256, 0, stream>>>(x, W1, dinv, bufH);
    k_gather<<<(NN + 3) / 4, 256, 0, stream>>>(cursor, srcSorted, dinv, bufH, bufA);
    k_stats<<<512, 256, 0, stream>>>(bufA, sum1, sq1);
    k_bnfin<<<1, 64, 0, stream>>>(sum1, sq1, g1, be1, scale1, shift1);

    // layer 2
    k_gemm2<<<(NN + 63) / 64, 256, 0, stream>>>(bufA, W2, scale1, shift1, dinv, bufH);
    k_gather<<<(NN + 3) / 4, 256, 0, stream>>>(cursor, srcSorted, dinv, bufH, bufA);
    k_stats<<<512, 256, 0, stream>>>(bufA, sum2, sq2);
    k_bnfin<<<1, 64, 0, stream>>>(sum2, sq2, g2, be2, scale2, shift2);

    // MLP head
    k_mlp<<<(NN + 255) / 256, 256, 0, stream>>>(bufA, scale2, shift2,
                                                Wm1, bm1, Wm2, bm2, Wm3, bm3, out);
}

// Round 5
// 389.747 us; speedup vs baseline: 2.3806x; 1.0075x over previous
//
#include <hip/hip_runtime.h>
#include <math.h>

#define NN 100000
#define NE 1200000
#define INC 128
#define HIDC 64
#define EPSV 1e-5f
#define SCAN_BS 1024
#define NBLK ((NN + SCAN_BS - 1) / SCAN_BS)   // 98
#define NPB 1024                               // nodes per bucket
#define NBUCK ((NN + NPB - 1) / NPB)           // 98
#define CHUNK 8192                             // edges per partA block

typedef float f4 __attribute__((ext_vector_type(4)));
typedef unsigned long long u64;

// ---------------- CSR build: count, scan ----------------

__global__ void k_count(const int* __restrict__ dst, int* cnt) {
    int e = blockIdx.x * blockDim.x + threadIdx.x;
    if (e < NE) atomicAdd(&cnt[dst[e]], 1);
}

__global__ __launch_bounds__(256) void k_scan1(const int* __restrict__ cnt, int* bsum) {
    __shared__ int part[256];
    int base = blockIdx.x * SCAN_BS + threadIdx.x * 4;
    int s = 0;
#pragma unroll
    for (int j = 0; j < 4; ++j) { int i = base + j; if (i < NN) s += cnt[i]; }
    part[threadIdx.x] = s;
    __syncthreads();
    for (int off = 128; off > 0; off >>= 1) {
        if (threadIdx.x < off) part[threadIdx.x] += part[threadIdx.x + off];
        __syncthreads();
    }
    if (threadIdx.x == 0) bsum[blockIdx.x] = part[0];
}

__global__ void k_scan2(int* bsum) {   // exclusive scan of NBLK block sums
    __shared__ int s[128];
    int t = threadIdx.x;
    if (t < NBLK) s[t] = bsum[t];
    __syncthreads();
    if (t == 0) {
        int acc = 0;
        for (int i = 0; i < NBLK; ++i) { int v = s[i]; s[i] = acc; acc += v; }
    }
    __syncthreads();
    if (t < NBLK) bsum[t] = s[t];
}

__global__ __launch_bounds__(256) void k_scan3(const int* __restrict__ cnt,
                                               const int* __restrict__ boff,
                                               int* cursor, float* dinv) {
    __shared__ int part[256];
    int t = threadIdx.x;
    int base = blockIdx.x * SCAN_BS + t * 4;
    int v[4]; int s = 0;
#pragma unroll
    for (int j = 0; j < 4; ++j) { int i = base + j; v[j] = (i < NN) ? cnt[i] : 0; s += v[j]; }
    part[t] = s;
    __syncthreads();
    for (int off = 1; off < 256; off <<= 1) {
        int x = (t >= off) ? part[t - off] : 0;
        __syncthreads();
        part[t] += x;
        __syncthreads();
    }
    int run = boff[blockIdx.x] + part[t] - s;
#pragma unroll
    for (int j = 0; j < 4; ++j) {
        int i = base + j;
        if (i < NN) {
            cursor[i] = run;
            dinv[i] = rsqrtf((float)v[j] + 1.0f);   // deg = indeg + self-loop
            run += v[j];
        }
    }
}

// bucketCur[b] = pair-region start for bucket b; cursor[NN] = NE sentinel
__global__ void k_binit(int* cursor, int* bucketCur) {
    int t = threadIdx.x;
    if (t < NBUCK) bucketCur[t] = cursor[t * NPB];
    if (t == 0) cursor[NN] = NE;
}

// ---- pass A: partition (src,dst) pairs into NBUCK bucket regions ----
__global__ __launch_bounds__(256) void k_partA(
    const int* __restrict__ src, const int* __restrict__ dst,
    int* bucketCur, u64* __restrict__ pairs) {
    __shared__ int hist[NBUCK], base[NBUCK];
    int t = threadIdx.x;
    if (t < NBUCK) hist[t] = 0;
    __syncthreads();
    int e0 = blockIdx.x * CHUNK;
    int dloc[32];
#pragma unroll
    for (int j = 0; j < 32; ++j) {
        int e = e0 + j * 256 + t;
        int d = (e < NE) ? dst[e] : -1;
        dloc[j] = d;
        if (d >= 0) atomicAdd(&hist[d >> 10], 1);
    }
    __syncthreads();
    if (t < NBUCK) base[t] = atomicAdd(&bucketCur[t], hist[t]);
    __syncthreads();
    if (t < NBUCK) hist[t] = 0;
    __syncthreads();
#pragma unroll
    for (int j = 0; j < 32; ++j) {
        int e = e0 + j * 256 + t;
        int d = dloc[j];
        if (d >= 0) {
            int b = d >> 10;
            int pos = base[b] + atomicAdd(&hist[b], 1);
            pairs[pos] = ((u64)(unsigned)d << 32) | (unsigned)src[e];
        }
    }
}

// ---- pass B: per-bucket local scatter into final srcSorted ----
__global__ __launch_bounds__(256) void k_partB(
    const int* __restrict__ cursor, const u64* __restrict__ pairs,
    int* __restrict__ srcSorted) {
    __shared__ int cur[NPB];
    int b = blockIdx.x, t = threadIdx.x;
    int nbase = b * NPB;
    for (int i = t; i < NPB; i += 256) {
        int node = nbase + i;
        cur[i] = (node < NN) ? cursor[node] : 0;
    }
    __syncthreads();
    int beg = cursor[nbase];
    int end = (nbase + NPB <= NN) ? cursor[nbase + NPB] : NE;
    for (int i = beg + t; i < end; i += 256) {
        u64 p = pairs[i];
        int d = (int)(p >> 32);
        int s = (int)(p & 0xffffffffu);
        int pos = atomicAdd(&cur[d - nbase], 1);
        srcSorted[pos] = s;
    }
}

// ---------------- layer-1 GEMM: h'[n] = dinv[n] * (x[n] @ W1) ----------------
__global__ __launch_bounds__(256) void k_gemm1(
    const float* __restrict__ x, const float* __restrict__ W,
    const float* __restrict__ dinv, float* __restrict__ hp) {
    __shared__ float xs[64 * 128];
    __shared__ float wsh[128 * 64];
    int tid = threadIdx.x;
    int nodeBase = blockIdx.x * 64;
    for (int idx = tid; idx < 128 * 64 / 4; idx += 256)
        *(f4*)&wsh[idx * 4] = *(const f4*)&W[idx * 4];
    for (int idx = tid; idx < 64 * 32; idx += 256) {
        int r = idx >> 5, k = (idx & 31) * 4;
        f4 v = {0.f, 0.f, 0.f, 0.f};
        int n = nodeBase + r;
        if (n < NN) v = *(const f4*)&x[(size_t)n * INC + k];
        *(f4*)&xs[r * 128 + ((k + (r & 3) * 4) & 127)] = v;
    }
    __syncthreads();
    int cg = tid & 15, ng = tid >> 4;
    int c0 = cg * 4, n0 = ng * 4;
    f4 acc0 = {0.f,0.f,0.f,0.f}, acc1 = acc0, acc2 = acc0, acc3 = acc0;
#pragma unroll 2
    for (int k0 = 0; k0 < INC; k0 += 4) {
        f4 xv0 = *(const f4*)&xs[(n0 + 0) * 128 + ((k0 + 0)  & 127)];
        f4 xv1 = *(const f4*)&xs[(n0 + 1) * 128 + ((k0 + 4)  & 127)];
        f4 xv2 = *(const f4*)&xs[(n0 + 2) * 128 + ((k0 + 8)  & 127)];
        f4 xv3 = *(const f4*)&xs[(n0 + 3) * 128 + ((k0 + 12) & 127)];
#pragma unroll
        for (int kk = 0; kk < 4; ++kk) {
            f4 wv = *(const f4*)&wsh[(k0 + kk) * 64 + c0];
            acc0 += xv0[kk] * wv;
            acc1 += xv1[kk] * wv;
            acc2 += xv2[kk] * wv;
            acc3 += xv3[kk] * wv;
        }
    }
    int n = nodeBase + n0;
    if (n + 0 < NN) *(f4*)&hp[(size_t)(n + 0) * HIDC + c0] = acc0 * dinv[n + 0];
    if (n + 1 < NN) *(f4*)&hp[(size_t)(n + 1) * HIDC + c0] = acc1 * dinv[n + 1];
    if (n + 2 < NN) *(f4*)&hp[(size_t)(n + 2) * HIDC + c0] = acc2 * dinv[n + 2];
    if (n + 3 < NN) *(f4*)&hp[(size_t)(n + 3) * HIDC + c0] = acc3 * dinv[n + 3];
}

// ---------------- layer-2 GEMM, BN+ReLU fused on the staged load ----------------
__global__ __launch_bounds__(256) void k_gemm2(
    const float* __restrict__ agg, const float* __restrict__ W,
    const float* __restrict__ scale, const float* __restrict__ shift,
    const float* __restrict__ dinv, float* __restrict__ hp) {
    __shared__ float xs[64 * 64];
    __shared__ float wsh[64 * 64];
    int tid = threadIdx.x;
    int nodeBase = blockIdx.x * 64;
    for (int idx = tid; idx < 64 * 64 / 4; idx += 256)
        *(f4*)&wsh[idx * 4] = *(const f4*)&W[idx * 4];
    for (int idx = tid; idx < 64 * 16; idx += 256) {
        int r = idx >> 4, c = (idx & 15) * 4;
        f4 v = {0.f, 0.f, 0.f, 0.f};
        int n = nodeBase + r;
        if (n < NN) {
            v = *(const f4*)&agg[(size_t)n * HIDC + c];
            f4 sc = *(const f4*)&scale[c];
            f4 sh = *(const f4*)&shift[c];
            v = v * sc + sh;
#pragma unroll
            for (int j = 0; j < 4; ++j) v[j] = fmaxf(v[j], 0.f);
        }
        *(f4*)&xs[r * 64 + ((c + (r & 3) * 4) & 63)] = v;
    }
    __syncthreads();
    int cg = tid & 15, ng = tid >> 4;
    int c0 = cg * 4, n0 = ng * 4;
    f4 acc0 = {0.f,0.f,0.f,0.f}, acc1 = acc0, acc2 = acc0, acc3 = acc0;
#pragma unroll 2
    for (int k0 = 0; k0 < HIDC; k0 += 4) {
        f4 xv0 = *(const f4*)&xs[(n0 + 0) * 64 + ((k0 + 0)  & 63)];
        f4 xv1 = *(const f4*)&xs[(n0 + 1) * 64 + ((k0 + 4)  & 63)];
        f4 xv2 = *(const f4*)&xs[(n0 + 2) * 64 + ((k0 + 8)  & 63)];
        f4 xv3 = *(const f4*)&xs[(n0 + 3) * 64 + ((k0 + 12) & 63)];
#pragma unroll
        for (int kk = 0; kk < 4; ++kk) {
            f4 wv = *(const f4*)&wsh[(k0 + kk) * 64 + c0];
            acc0 += xv0[kk] * wv;
            acc1 += xv1[kk] * wv;
            acc2 += xv2[kk] * wv;
            acc3 += xv3[kk] * wv;
        }
    }
    int n = nodeBase + n0;
    if (n + 0 < NN) *(f4*)&hp[(size_t)(n + 0) * HIDC + c0] = acc0 * dinv[n + 0];
    if (n + 1 < NN) *(f4*)&hp[(size_t)(n + 1) * HIDC + c0] = acc1 * dinv[n + 1];
    if (n + 2 < NN) *(f4*)&hp[(size_t)(n + 2) * HIDC + c0] = acc2 * dinv[n + 2];
    if (n + 3 < NN) *(f4*)&hp[(size_t)(n + 3) * HIDC + c0] = acc3 * dinv[n + 3];
}

// ---------------- CSR gather: agg[n] = dinv[n] * (h'[n] + sum h'[s]) ----------------
__global__ __launch_bounds__(256) void k_gather(
    const int* __restrict__ cursor, const int* __restrict__ srcSorted,
    const float* __restrict__ dinv, const float* __restrict__ hp,
    float* __restrict__ agg) {
    int wid = threadIdx.x >> 6, lane = threadIdx.x & 63;
    int n = blockIdx.x * 4 + wid;
    if (n >= NN) return;
    int beg = cursor[n];
    int end = cursor[n + 1];
    float acc = hp[(size_t)n * HIDC + lane];   // self-loop
    for (int base = beg; base < end; base += 64) {
        int m = end - base; if (m > 64) m = 64;
        int si = (base + lane < end) ? srcSorted[base + lane] : 0;
        int j = 0;
        for (; j + 8 <= m; j += 8) {
            int s0 = __shfl(si, j),     s1 = __shfl(si, j + 1);
            int s2 = __shfl(si, j + 2), s3 = __shfl(si, j + 3);
            int s4 = __shfl(si, j + 4), s5 = __shfl(si, j + 5);
            int s6 = __shfl(si, j + 6), s7 = __shfl(si, j + 7);
            float v0 = hp[(size_t)s0 * HIDC + lane];
            float v1 = hp[(size_t)s1 * HIDC + lane];
            float v2 = hp[(size_t)s2 * HIDC + lane];
            float v3 = hp[(size_t)s3 * HIDC + lane];
            float v4 = hp[(size_t)s4 * HIDC + lane];
            float v5 = hp[(size_t)s5 * HIDC + lane];
            float v6 = hp[(size_t)s6 * HIDC + lane];
            float v7 = hp[(size_t)s7 * HIDC + lane];
            acc += ((v0 + v1) + (v2 + v3)) + ((v4 + v5) + (v6 + v7));
        }
        for (; j + 2 <= m; j += 2) {
            int s0 = __shfl(si, j), s1 = __shfl(si, j + 1);
            float v0 = hp[(size_t)s0 * HIDC + lane];
            float v1 = hp[(size_t)s1 * HIDC + lane];
            acc += v0 + v1;
        }
        if (j < m) {
            int s = __shfl(si, j);
            acc += hp[(size_t)s * HIDC + lane];
        }
    }
    agg[(size_t)n * HIDC + lane] = dinv[n] * acc;
}

// ---------------- BN statistics ----------------
__global__ __launch_bounds__(256) void k_stats(
    const float* __restrict__ agg, float* gsum, float* gsq) {
    __shared__ float ls[256], lq[256];
    int tid = threadIdx.x;
    int c = tid & 63, r = tid >> 6;
    float s = 0.0f, q = 0.0f;
    for (int n = blockIdx.x * 4 + r; n < NN; n += gridDim.x * 4) {
        float v = agg[(size_t)n * HIDC + c];
        s += v; q += v * v;
    }
    ls[tid] = s; lq[tid] = q;
    __syncthreads();
    if (tid < 64) {
        s = ls[tid] + ls[tid + 64] + ls[tid + 128] + ls[tid + 192];
        q = lq[tid] + lq[tid + 64] + lq[tid + 128] + lq[tid + 192];
        atomicAdd(&gsum[c], s);
        atomicAdd(&gsq[c], q);
    }
}

__global__ void k_bnfin(const float* __restrict__ gsum, const float* __restrict__ gsq,
                        const float* __restrict__ g, const float* __restrict__ be,
                        float* scale, float* shift) {
    int c = threadIdx.x;
    if (c < HIDC) {
        float mu = gsum[c] * (1.0f / NN);
        float var = gsq[c] * (1.0f / NN) - mu * mu;
        float inv = rsqrtf(var + EPSV);
        float sc = g[c] * inv;
        scale[c] = sc;
        shift[c] = be[c] - mu * sc;
    }
}

// ---------------- MLP head with fused BN+ReLU on the load ----------------
__global__ __launch_bounds__(256) void k_mlp(
    const float* __restrict__ agg, const float* __restrict__ scale,
    const float* __restrict__ shift,
    const float* __restrict__ Wm1, const float* __restrict__ bm1,
    const float* __restrict__ Wm2, const float* __restrict__ bm2,
    const float* __restrict__ Wm3, const float* __restrict__ bm3,
    float* __restrict__ out) {
    int n = blockIdx.x * blockDim.x + threadIdx.x;
    if (n >= NN) return;
    float h[HIDC];
#pragma unroll
    for (int c = 0; c < HIDC; ++c)
        h[c] = fmaxf(agg[(size_t)n * HIDC + c] * scale[c] + shift[c], 0.0f);
    float a1[32];
#pragma unroll
    for (int j = 0; j < 32; ++j) {
        float acc = bm1[j];
#pragma unroll
        for (int c = 0; c < HIDC; ++c) acc += h[c] * Wm1[c * 32 + j];
        a1[j] = fmaxf(acc, 0.0f);
    }
    float a2[16];
#pragma unroll
    for (int j = 0; j < 16; ++j) {
        float acc = bm2[j];
#pragma unroll
        for (int c = 0; c < 32; ++c) acc += a1[c] * Wm2[c * 16 + j];
        a2[j] = fmaxf(acc, 0.0f);
    }
    float z = bm3[0];
#pragma unroll
    for (int c = 0; c < 16; ++c) z += a2[c] * Wm3[c];
    out[n] = 1.0f / (1.0f + expf(-z));
}

extern "C" void kernel_launch(void* const* d_in, const int* in_sizes, int n_in,
                              void* d_out, int out_size, void* d_ws, size_t ws_size,
                              hipStream_t stream) {
    const float* x   = (const float*)d_in[0];
    const int*   ei  = (const int*)d_in[1];
    const float* W1  = (const float*)d_in[2];
    // b1 (d_in[3]) cancels in BatchNorm
    const float* g1  = (const float*)d_in[4];
    const float* be1 = (const float*)d_in[5];
    const float* W2  = (const float*)d_in[6];
    // b2 (d_in[7]) cancels in BatchNorm
    const float* g2  = (const float*)d_in[8];
    const float* be2 = (const float*)d_in[9];
    const float* Wm1 = (const float*)d_in[10];
    const float* bm1 = (const float*)d_in[11];
    const float* Wm2 = (const float*)d_in[12];
    const float* bm2 = (const float*)d_in[13];
    const float* Wm3 = (const float*)d_in[14];
    const float* bm3 = (const float*)d_in[15];
    float* out = (float*)d_out;

    const int* srcI = ei;
    const int* dstI = ei + NE;

    // layout (ints); bufH start is 8B-aligned so pairs can alias it
    int*   cnt       = (int*)d_ws;                      // 100000
    int*   bsum      = cnt + NN;                        // 128 (scan sums, then bucketCur)
    int*   cursor    = bsum + 128;                      // NN+4 (starts; cursor[NN]=NE sentinel)
    int*   srcSorted = cursor + NN + 4;                 // NE
    float* dinv      = (float*)(srcSorted + NE);        // NN
    float* bufH      = dinv + NN;                       // NN*64  (h' = dinv*h)
    float* bufA      = bufH + (size_t)NN * HIDC;        // NN*64
    float* stats     = bufA + (size_t)NN * HIDC;        // 512
    u64*   pairs     = (u64*)bufH;                      // NE u64, aliases bufH (dead here)
    float *sum1 = stats,       *sq1 = stats + 64;
    float *sum2 = stats + 128, *sq2 = stats + 192;
    float *scale1 = stats + 256, *shift1 = stats + 320;
    float *scale2 = stats + 384, *shift2 = stats + 448;

    hipMemsetAsync(cnt, 0, NN * sizeof(int), stream);
    hipMemsetAsync(stats, 0, 256 * sizeof(float), stream);

    // CSR build (by destination): count -> scan -> bucketed 2-pass fill
    k_count<<<(NE + 255) / 256, 256, 0, stream>>>(dstI, cnt);
    k_scan1<<<NBLK, 256, 0, stream>>>(cnt, bsum);
    k_scan2<<<1, 128, 0, stream>>>(bsum);
    k_scan3<<<NBLK, 256, 0, stream>>>(cnt, bsum, cursor, dinv);
    k_binit<<<1, 128, 0, stream>>>(cursor, bsum);       // bsum reused as bucketCur
    k_partA<<<(NE + CHUNK - 1) / CHUNK, 256, 0, stream>>>(srcI, dstI, bsum, pairs);
    k_partB<<<NBUCK, 256, 0, stream>>>(cursor, pairs, srcSorted);

    // layer 1
    k_gemm1<<<(NN + 63) / 64, 256, 0, stream>>>(x, W1, dinv, bufH);
    k_gather<<<(NN + 3) / 4, 256, 0, stream>>>(cursor, srcSorted, dinv, bufH, bufA);
    k_stats<<<512, 256, 0, stream>>>(bufA, sum1, sq1);
    k_bnfin<<<1, 64, 0, stream>>>(sum1, sq1, g1, be1, scale1, shift1);

    // layer 2
    k_gemm2<<<(NN + 63) / 64, 256, 0, stream>>>(bufA, W2, scale1, shift1, dinv, bufH);
    k_gather<<<(NN + 3) / 4, 256, 0, stream>>>(cursor, srcSorted, dinv, bufH, bufA);
    k_stats<<<512, 256, 0, stream>>>(bufA, sum2, sq2);
    k_bnfin<<<1, 64, 0, stream>>>(sum2, sq2, g2, be2, scale2, shift2);

    // MLP head
    k_mlp<<<(NN + 255) / 256, 256, 0, stream>>>(bufA, scale2, shift2,
                                                Wm1, bm1, Wm2, bm2, Wm3, bm3, out);
}

// Round 6
// 311.466 us; speedup vs baseline: 2.9789x; 1.2513x over previous
//
#include <hip/hip_runtime.h>
#include <hip/hip_fp16.h>
#include <math.h>

#define NN 100000
#define NE 1200000
#define INC 128
#define HIDC 64
#define EPSV 1e-5f
#define NPB 1024                               // nodes per bucket
#define NBUCK ((NN + NPB - 1) / NPB)           // 98
#define CHUNK 8192                             // edges per partA/hist block

typedef float f4 __attribute__((ext_vector_type(4)));
typedef _Float16 hf;
typedef _Float16 h4 __attribute__((ext_vector_type(4)));
typedef unsigned long long u64;

// ---- bucket histogram: 98 global atomics per block ----
__global__ __launch_bounds__(256) void k_hist(const int* __restrict__ dst, int* bucketTotal) {
    __shared__ int hist[NBUCK];
    int t = threadIdx.x;
    if (t < NBUCK) hist[t] = 0;
    __syncthreads();
    int e0 = blockIdx.x * CHUNK;
#pragma unroll
    for (int j = 0; j < CHUNK / 256; ++j) {
        int e = e0 + j * 256 + t;
        if (e < NE) atomicAdd(&hist[dst[e] >> 10], 1);
    }
    __syncthreads();
    if (t < NBUCK && hist[t]) atomicAdd(&bucketTotal[t], hist[t]);
}

// ---- scan 98 bucket totals -> bucketStart/bucketCur; sentinels ----
__global__ void k_bscan(const int* __restrict__ bucketTotal,
                        int* bucketStart, int* bucketCur, int* cursor) {
    __shared__ int s[NBUCK];
    int t = threadIdx.x;
    if (t < NBUCK) s[t] = bucketTotal[t];
    __syncthreads();
    if (t == 0) {
        int acc = 0;
        for (int i = 0; i < NBUCK; ++i) { int v = s[i]; s[i] = acc; acc += v; }
    }
    __syncthreads();
    if (t < NBUCK) { bucketStart[t] = s[t]; bucketCur[t] = s[t]; }
    if (t == 0) { bucketStart[NBUCK] = NE; cursor[NN] = NE; }
}

// ---- pass A: partition (src,dst) pairs into bucket regions ----
__global__ __launch_bounds__(256) void k_partA(
    const int* __restrict__ src, const int* __restrict__ dst,
    int* bucketCur, u64* __restrict__ pairs) {
    __shared__ int hist[NBUCK], base[NBUCK];
    int t = threadIdx.x;
    if (t < NBUCK) hist[t] = 0;
    __syncthreads();
    int e0 = blockIdx.x * CHUNK;
    int dloc[32];
#pragma unroll
    for (int j = 0; j < 32; ++j) {
        int e = e0 + j * 256 + t;
        int d = (e < NE) ? dst[e] : -1;
        dloc[j] = d;
        if (d >= 0) atomicAdd(&hist[d >> 10], 1);
    }
    __syncthreads();
    if (t < NBUCK) base[t] = atomicAdd(&bucketCur[t], hist[t]);
    __syncthreads();
    if (t < NBUCK) hist[t] = 0;
    __syncthreads();
#pragma unroll
    for (int j = 0; j < 32; ++j) {
        int e = e0 + j * 256 + t;
        int d = dloc[j];
        if (d >= 0) {
            int b = d >> 10;
            int pos = base[b] + atomicAdd(&hist[b], 1);
            pairs[pos] = ((u64)(unsigned)d << 32) | (unsigned)src[e];
        }
    }
}

// ---- pass B: per-bucket counts (LDS) -> cursor/dinv; local scatter ----
__global__ __launch_bounds__(256) void k_partB(
    const int* __restrict__ bucketStart, const u64* __restrict__ pairs,
    int* __restrict__ srcSorted, int* __restrict__ cursor, float* __restrict__ dinv) {
    __shared__ int cnt1024[NPB];
    __shared__ int off1024[NPB];
    __shared__ int part[256];
    int b = blockIdx.x, t = threadIdx.x;
    int nbase = b * NPB;
    int beg = bucketStart[b], end = bucketStart[b + 1];
    for (int i = t; i < NPB; i += 256) cnt1024[i] = 0;
    __syncthreads();
    for (int i = beg + t; i < end; i += 256)
        atomicAdd(&cnt1024[(int)(pairs[i] >> 32) - nbase], 1);
    __syncthreads();
    int c[4]; int s = 0;
#pragma unroll
    for (int j = 0; j < 4; ++j) { c[j] = cnt1024[t * 4 + j]; s += c[j]; }
    part[t] = s;
    __syncthreads();
    for (int off = 1; off < 256; off <<= 1) {
        int x = (t >= off) ? part[t - off] : 0;
        __syncthreads();
        part[t] += x;
        __syncthreads();
    }
    int run = part[t] - s;   // exclusive prefix within bucket
#pragma unroll
    for (int j = 0; j < 4; ++j) {
        int node = nbase + t * 4 + j;
        if (node < NN) {
            cursor[node] = beg + run;
            off1024[t * 4 + j] = run;
            dinv[node] = rsqrtf((float)c[j] + 1.0f);   // deg = indeg + self-loop
            run += c[j];
        }
    }
    __syncthreads();
    for (int i = beg + t; i < end; i += 256) {
        u64 p = pairs[i];
        int d = (int)(p >> 32);
        int pos = beg + atomicAdd(&off1024[d - nbase], 1);
        srcSorted[pos] = (int)(p & 0xffffffffu);
    }
}

// ---------------- layer-1 GEMM: hp[n] = fp16( dinv[n] * (x[n] @ W1) ) ----------------
__global__ __launch_bounds__(256) void k_gemm1(
    const float* __restrict__ x, const float* __restrict__ W,
    const float* __restrict__ dinv, hf* __restrict__ hp) {
    __shared__ float xs[64 * 128];
    __shared__ float wsh[128 * 64];
    int tid = threadIdx.x;
    int nodeBase = blockIdx.x * 64;
    for (int idx = tid; idx < 128 * 64 / 4; idx += 256)
        *(f4*)&wsh[idx * 4] = *(const f4*)&W[idx * 4];
    for (int idx = tid; idx < 64 * 32; idx += 256) {
        int r = idx >> 5, k = (idx & 31) * 4;
        f4 v = {0.f, 0.f, 0.f, 0.f};
        int n = nodeBase + r;
        if (n < NN) v = *(const f4*)&x[(size_t)n * INC + k];
        *(f4*)&xs[r * 128 + ((k + (r & 3) * 4) & 127)] = v;
    }
    __syncthreads();
    int cg = tid & 15, ng = tid >> 4;
    int c0 = cg * 4, n0 = ng * 4;
    f4 acc0 = {0.f,0.f,0.f,0.f}, acc1 = acc0, acc2 = acc0, acc3 = acc0;
#pragma unroll 2
    for (int k0 = 0; k0 < INC; k0 += 4) {
        f4 xv0 = *(const f4*)&xs[(n0 + 0) * 128 + ((k0 + 0)  & 127)];
        f4 xv1 = *(const f4*)&xs[(n0 + 1) * 128 + ((k0 + 4)  & 127)];
        f4 xv2 = *(const f4*)&xs[(n0 + 2) * 128 + ((k0 + 8)  & 127)];
        f4 xv3 = *(const f4*)&xs[(n0 + 3) * 128 + ((k0 + 12) & 127)];
#pragma unroll
        for (int kk = 0; kk < 4; ++kk) {
            f4 wv = *(const f4*)&wsh[(k0 + kk) * 64 + c0];
            acc0 += xv0[kk] * wv;
            acc1 += xv1[kk] * wv;
            acc2 += xv2[kk] * wv;
            acc3 += xv3[kk] * wv;
        }
    }
    int n = nodeBase + n0;
#pragma unroll
    for (int q = 0; q < 4; ++q) {
        int nn = n + q;
        if (nn < NN) {
            f4 a = (q == 0) ? acc0 : (q == 1) ? acc1 : (q == 2) ? acc2 : acc3;
            float d = dinv[nn];
            h4 o;
#pragma unroll
            for (int j = 0; j < 4; ++j) o[j] = (hf)(a[j] * d);
            *(h4*)&hp[(size_t)nn * HIDC + c0] = o;
        }
    }
}

// ---------------- layer-2 GEMM, BN+ReLU fused on the staged load ----------------
__global__ __launch_bounds__(256) void k_gemm2(
    const float* __restrict__ agg, const float* __restrict__ W,
    const float* __restrict__ scale, const float* __restrict__ shift,
    const float* __restrict__ dinv, hf* __restrict__ hp) {
    __shared__ float xs[64 * 64];
    __shared__ float wsh[64 * 64];
    int tid = threadIdx.x;
    int nodeBase = blockIdx.x * 64;
    for (int idx = tid; idx < 64 * 64 / 4; idx += 256)
        *(f4*)&wsh[idx * 4] = *(const f4*)&W[idx * 4];
    for (int idx = tid; idx < 64 * 16; idx += 256) {
        int r = idx >> 4, c = (idx & 15) * 4;
        f4 v = {0.f, 0.f, 0.f, 0.f};
        int n = nodeBase + r;
        if (n < NN) {
            v = *(const f4*)&agg[(size_t)n * HIDC + c];
            f4 sc = *(const f4*)&scale[c];
            f4 sh = *(const f4*)&shift[c];
            v = v * sc + sh;
#pragma unroll
            for (int j = 0; j < 4; ++j) v[j] = fmaxf(v[j], 0.f);
        }
        *(f4*)&xs[r * 64 + ((c + (r & 3) * 4) & 63)] = v;
    }
    __syncthreads();
    int cg = tid & 15, ng = tid >> 4;
    int c0 = cg * 4, n0 = ng * 4;
    f4 acc0 = {0.f,0.f,0.f,0.f}, acc1 = acc0, acc2 = acc0, acc3 = acc0;
#pragma unroll 2
    for (int k0 = 0; k0 < HIDC; k0 += 4) {
        f4 xv0 = *(const f4*)&xs[(n0 + 0) * 64 + ((k0 + 0)  & 63)];
        f4 xv1 = *(const f4*)&xs[(n0 + 1) * 64 + ((k0 + 4)  & 63)];
        f4 xv2 = *(const f4*)&xs[(n0 + 2) * 64 + ((k0 + 8)  & 63)];
        f4 xv3 = *(const f4*)&xs[(n0 + 3) * 64 + ((k0 + 12) & 63)];
#pragma unroll
        for (int kk = 0; kk < 4; ++kk) {
            f4 wv = *(const f4*)&wsh[(k0 + kk) * 64 + c0];
            acc0 += xv0[kk] * wv;
            acc1 += xv1[kk] * wv;
            acc2 += xv2[kk] * wv;
            acc3 += xv3[kk] * wv;
        }
    }
    int n = nodeBase + n0;
#pragma unroll
    for (int q = 0; q < 4; ++q) {
        int nn = n + q;
        if (nn < NN) {
            f4 a = (q == 0) ? acc0 : (q == 1) ? acc1 : (q == 2) ? acc2 : acc3;
            float d = dinv[nn];
            h4 o;
#pragma unroll
            for (int j = 0; j < 4; ++j) o[j] = (hf)(a[j] * d);
            *(h4*)&hp[(size_t)nn * HIDC + c0] = o;
        }
    }
}

// ---------------- CSR gather (fp16 table): agg[n] = dinv[n]*(hp[n] + sum hp[s]) ----------------
__global__ __launch_bounds__(256) void k_gather(
    const int* __restrict__ cursor, const int* __restrict__ srcSorted,
    const float* __restrict__ dinv, const hf* __restrict__ hp,
    float* __restrict__ agg) {
    int wid = threadIdx.x >> 6, lane = threadIdx.x & 63;
    int n = blockIdx.x * 4 + wid;
    if (n >= NN) return;
    int beg = cursor[n];
    int end = cursor[n + 1];
    float acc = (float)hp[(size_t)n * HIDC + lane];   // self-loop
    for (int base = beg; base < end; base += 64) {
        int m = end - base; if (m > 64) m = 64;
        int si = (base + lane < end) ? srcSorted[base + lane] : 0;
        int j = 0;
        for (; j + 8 <= m; j += 8) {
            int s0 = __shfl(si, j),     s1 = __shfl(si, j + 1);
            int s2 = __shfl(si, j + 2), s3 = __shfl(si, j + 3);
            int s4 = __shfl(si, j + 4), s5 = __shfl(si, j + 5);
            int s6 = __shfl(si, j + 6), s7 = __shfl(si, j + 7);
            float v0 = (float)hp[(size_t)s0 * HIDC + lane];
            float v1 = (float)hp[(size_t)s1 * HIDC + lane];
            float v2 = (float)hp[(size_t)s2 * HIDC + lane];
            float v3 = (float)hp[(size_t)s3 * HIDC + lane];
            float v4 = (float)hp[(size_t)s4 * HIDC + lane];
            float v5 = (float)hp[(size_t)s5 * HIDC + lane];
            float v6 = (float)hp[(size_t)s6 * HIDC + lane];
            float v7 = (float)hp[(size_t)s7 * HIDC + lane];
            acc += ((v0 + v1) + (v2 + v3)) + ((v4 + v5) + (v6 + v7));
        }
        for (; j + 2 <= m; j += 2) {
            int s0 = __shfl(si, j), s1 = __shfl(si, j + 1);
            float v0 = (float)hp[(size_t)s0 * HIDC + lane];
            float v1 = (float)hp[(size_t)s1 * HIDC + lane];
            acc += v0 + v1;
        }
        if (j < m) {
            int s = __shfl(si, j);
            acc += (float)hp[(size_t)s * HIDC + lane];
        }
    }
    agg[(size_t)n * HIDC + lane] = dinv[n] * acc;
}

// ---------------- BN statistics ----------------
__global__ __launch_bounds__(256) void k_stats(
    const float* __restrict__ agg, float* gsum, float* gsq) {
    __shared__ float ls[256], lq[256];
    int tid = threadIdx.x;
    int c = tid & 63, r = tid >> 6;
    float s = 0.0f, q = 0.0f;
    for (int n = blockIdx.x * 4 + r; n < NN; n += gridDim.x * 4) {
        float v = agg[(size_t)n * HIDC + c];
        s += v; q += v * v;
    }
    ls[tid] = s; lq[tid] = q;
    __syncthreads();
    if (tid < 64) {
        s = ls[tid] + ls[tid + 64] + ls[tid + 128] + ls[tid + 192];
        q = lq[tid] + lq[tid + 64] + lq[tid + 128] + lq[tid + 192];
        atomicAdd(&gsum[c], s);
        atomicAdd(&gsq[c], q);
    }
}

__global__ void k_bnfin(const float* __restrict__ gsum, const float* __restrict__ gsq,
                        const float* __restrict__ g, const float* __restrict__ be,
                        float* scale, float* shift) {
    int c = threadIdx.x;
    if (c < HIDC) {
        float mu = gsum[c] * (1.0f / NN);
        float var = gsq[c] * (1.0f / NN) - mu * mu;
        float inv = rsqrtf(var + EPSV);
        float sc = g[c] * inv;
        scale[c] = sc;
        shift[c] = be[c] - mu * sc;
    }
}

// ---------------- MLP head with fused BN+ReLU on the load ----------------
__global__ __launch_bounds__(256) void k_mlp(
    const float* __restrict__ agg, const float* __restrict__ scale,
    const float* __restrict__ shift,
    const float* __restrict__ Wm1, const float* __restrict__ bm1,
    const float* __restrict__ Wm2, const float* __restrict__ bm2,
    const float* __restrict__ Wm3, const float* __restrict__ bm3,
    float* __restrict__ out) {
    int n = blockIdx.x * blockDim.x + threadIdx.x;
    if (n >= NN) return;
    float h[HIDC];
#pragma unroll
    for (int c = 0; c < HIDC; ++c)
        h[c] = fmaxf(agg[(size_t)n * HIDC + c] * scale[c] + shift[c], 0.0f);
    float a1[32];
#pragma unroll
    for (int j = 0; j < 32; ++j) {
        float acc = bm1[j];
#pragma unroll
        for (int c = 0; c < HIDC; ++c) acc += h[c] * Wm1[c * 32 + j];
        a1[j] = fmaxf(acc, 0.0f);
    }
    float a2[16];
#pragma unroll
    for (int j = 0; j < 16; ++j) {
        float acc = bm2[j];
#pragma unroll
        for (int c = 0; c < 32; ++c) acc += a1[c] * Wm2[c * 16 + j];
        a2[j] = fmaxf(acc, 0.0f);
    }
    float z = bm3[0];
#pragma unroll
    for (int c = 0; c < 16; ++c) z += a2[c] * Wm3[c];
    out[n] = 1.0f / (1.0f + expf(-z));
}

extern "C" void kernel_launch(void* const* d_in, const int* in_sizes, int n_in,
                              void* d_out, int out_size, void* d_ws, size_t ws_size,
                              hipStream_t stream) {
    const float* x   = (const float*)d_in[0];
    const int*   ei  = (const int*)d_in[1];
    const float* W1  = (const float*)d_in[2];
    // b1 (d_in[3]) cancels in BatchNorm
    const float* g1  = (const float*)d_in[4];
    const float* be1 = (const float*)d_in[5];
    const float* W2  = (const float*)d_in[6];
    // b2 (d_in[7]) cancels in BatchNorm
    const float* g2  = (const float*)d_in[8];
    const float* be2 = (const float*)d_in[9];
    const float* Wm1 = (const float*)d_in[10];
    const float* bm1 = (const float*)d_in[11];
    const float* Wm2 = (const float*)d_in[12];
    const float* bm2 = (const float*)d_in[13];
    const float* Wm3 = (const float*)d_in[14];
    const float* bm3 = (const float*)d_in[15];
    float* out = (float*)d_out;

    const int* srcI = ei;
    const int* dstI = ei + NE;

    int*   bucketTotal = (int*)d_ws;                    // 128
    int*   bucketStart = bucketTotal + 128;             // 128 (NBUCK+1)
    int*   bucketCur   = bucketStart + 128;             // 128
    int*   cursor      = bucketCur + 128;               // NN+4
    int*   srcSorted   = cursor + NN + 4;               // NE
    float* dinv        = (float*)(srcSorted + NE);      // NN
    hf*    hp          = (hf*)(dinv + NN);              // NN*64 fp16 (12.8 MB)
    float* bufA        = (float*)(hp + (size_t)NN * HIDC);  // NN*64 fp32
    float* stats       = bufA + (size_t)NN * HIDC;      // 512
    u64*   pairs       = (u64*)hp;                      // NE u64, aliases hp (dead until gemm1)
    float *sum1 = stats,       *sq1 = stats + 64;
    float *sum2 = stats + 128, *sq2 = stats + 192;
    float *scale1 = stats + 256, *shift1 = stats + 320;
    float *scale2 = stats + 384, *shift2 = stats + 448;

    hipMemsetAsync(bucketTotal, 0, 128 * sizeof(int), stream);
    hipMemsetAsync(stats, 0, 256 * sizeof(float), stream);

    // CSR build: bucket hist -> bucket scan -> partition -> per-bucket finalize
    k_hist<<<(NE + CHUNK - 1) / CHUNK, 256, 0, stream>>>(dstI, bucketTotal);
    k_bscan<<<1, 128, 0, stream>>>(bucketTotal, bucketStart, bucketCur, cursor);
    k_partA<<<(NE + CHUNK - 1) / CHUNK, 256, 0, stream>>>(srcI, dstI, bucketCur, pairs);
    k_partB<<<NBUCK, 256, 0, stream>>>(bucketStart, pairs, srcSorted, cursor, dinv);

    // layer 1
    k_gemm1<<<(NN + 63) / 64, 256, 0, stream>>>(x, W1, dinv, hp);
    k_gather<<<(NN + 3) / 4, 256, 0, stream>>>(cursor, srcSorted, dinv, hp, bufA);
    k_stats<<<512, 256, 0, stream>>>(bufA, sum1, sq1);
    k_bnfin<<<1, 64, 0, stream>>>(sum1, sq1, g1, be1, scale1, shift1);

    // layer 2
    k_gemm2<<<(NN + 63) / 64, 256, 0, stream>>>(bufA, W2, scale1, shift1, dinv, hp);
    k_gather<<<(NN + 3) / 4, 256, 0, stream>>>(cursor, srcSorted, dinv, hp, bufA);
    k_stats<<<512, 256, 0, stream>>>(bufA, sum2, sq2);
    k_bnfin<<<1, 64, 0, stream>>>(sum2, sq2, g2, be2, scale2, shift2);

    // MLP head
    k_mlp<<<(NN + 255) / 256, 256, 0, stream>>>(bufA, scale2, shift2,
                                                Wm1, bm1, Wm2, bm2, Wm3, bm3, out);
}